// Round 1
// baseline (63.503 us; speedup 1.0000x reference)
//
#include <hip/hip_runtime.h>

// out[b,o] = bias[o] + sum_j sum_{d=1..3} coeff[o*128+j, d] * x[b,j]^d
//   bias[o] = sum_j coeff[o*128+j, 0]   (x^0 term is a constant -> epilogue)
//
// GEMM: out[M=8192, N=128] = P[M, K=384] * W[N, K=384]^T + bias
//   k = d_idx*128 + j  (d-major), d_idx=0,1,2 -> power d_idx+1
//   P[b,k] = x[b,j]^(d_idx+1), W[o,k] = coeff[o*128+j, d_idx+1]
//
// R4 changes vs R3-best (61 us composite):
//  - K 512 -> 384: d=0 slice removed from MFMA; bias = fp32 side-sum (8
//    lanes/o + shfl_xor), added in epilogue. -25% MFMA/LDS/convert work,
//    better accuracy (bias now exact fp32).
//  - Whole A tile (64 x 384 bf16, 50 KB) staged ONCE: no stage loop, no
//    double buffer, no prefetch regs -> ONE __syncthreads in the kernel.
//    12 fully-unrolled k-steps: 36 independent ds_read_b128 + 24 MFMA,
//    compiler schedules with fine lgkmcnt (no per-stage barrier drains).
//  - d-major packing keeps every LDS store aligned (uint / uint2).
// Block 256 thr = 4 waves, tile 64Mx32N (wave: 16Mx32N). LDS 75.4 KB ->
// 2 blocks/CU. Grid (128,4) = 512 blocks = exactly 2/CU.

#define BATCH   8192
#define IN_DIM  128
#define OUT_DIM 128
#define KDIM    512            // raw coeff row length (floats)
#define KP      384            // packed K
#define M_BLK   64
#define N_BLK   32
#define WPAD    392            // W row stride, bf16 units (384 + 8)
#define APAD    392            // A row stride, bf16 units (384 + 8)

typedef __attribute__((ext_vector_type(8))) short bf16x8;
typedef __attribute__((ext_vector_type(4))) float f32x4;

__device__ inline unsigned short f2bf(float f) {
    union { float f; unsigned int u; } v; v.f = f;
    unsigned int u = v.u;
    u += 0x7FFFu + ((u >> 16) & 1u);   // round-to-nearest-even
    return (unsigned short)(u >> 16);
}

#if defined(__has_builtin)
#if __has_builtin(__builtin_amdgcn_cvt_pk_bf16_f32)
#define HAVE_HW_PKBF16 1
#endif
#endif

#ifdef HAVE_HW_PKBF16
typedef __attribute__((ext_vector_type(2))) __bf16 bf16x2_t;
__device__ inline unsigned int pk2(float a, float b) {
    bf16x2_t r = __builtin_amdgcn_cvt_pk_bf16_f32(a, b);
    union { bf16x2_t v; unsigned int u; } c; c.v = r; return c.u;
}
#else
__device__ inline unsigned int pk2(float a, float b) {
    return (unsigned int)f2bf(a) | ((unsigned int)f2bf(b) << 16);
}
#endif

__global__ __launch_bounds__(256, 2) void kan_mfma(const float* __restrict__ x,
                                                   const float* __restrict__ coeff,
                                                   float* __restrict__ out) {
    __shared__ __align__(16) unsigned short W_lds[N_BLK * WPAD];   // 25.1 KB
    __shared__ __align__(16) unsigned short A_lds[M_BLK * APAD];   // 50.2 KB
    __shared__ float bias_lds[N_BLK];

    const int t    = threadIdx.x;
    const int w    = t >> 6;          // wave 0..3 -> M sub-tile
    const int lane = t & 63;
    const int q    = lane >> 4;
    const int r    = lane & 15;
    const int m0   = blockIdx.x * M_BLK;
    const int n0   = blockIdx.y * N_BLK;

    // ---- W staging (once): 32 rows x 512 f32 -> d-major bf16 LDS ----
    // thread: one row per i, j-pair (jl, jl+1); 32B contiguous per lane.
    {
        const int jl = lane * 2;               // even j, 0..126
        #pragma unroll
        for (int i = 0; i < 8; ++i) {
            const int row = i * 4 + w;
            const float* cp = &coeff[(size_t)(n0 + row) * KDIM + (size_t)jl * 4];
            const float4 cA = *(const float4*)cp;        // j = jl   : {c0,c1,c2,c3}
            const float4 cB = *(const float4*)(cp + 4);  // j = jl+1
            unsigned short* Wr = &W_lds[row * WPAD + jl];
            *(unsigned int*)(Wr)       = pk2(cA.y, cB.y);   // d=1 block
            *(unsigned int*)(Wr + 128) = pk2(cA.z, cB.z);   // d=2 block
            *(unsigned int*)(Wr + 256) = pk2(cA.w, cB.w);   // d=3 block
        }
    }

    // ---- bias[o] = sum_j c0[o,j], fp32, 8 lanes per o (L2-hot re-read) ----
    {
        const int o = w * 8 + (lane >> 3);      // local o 0..31, each once
        const float* cp = &coeff[(size_t)(n0 + o) * KDIM + (size_t)(lane & 7) * 64];
        float bsum = 0.f;
        #pragma unroll
        for (int jj = 0; jj < 16; ++jj) bsum += cp[jj * 4];
        bsum += __shfl_xor(bsum, 1);
        bsum += __shfl_xor(bsum, 2);
        bsum += __shfl_xor(bsum, 4);
        if ((lane & 7) == 0) bias_lds[o] = bsum;
    }

    // ---- A staging (once): 64 rows x 128 x f32 -> powers, d-major bf16 ----
    #pragma unroll
    for (int i = 0; i < 8; ++i) {
        const int f   = i * 256 + t;
        const int row = f >> 5;                 // 32 float4 per row
        const int c4  = f & 31;
        const float4 v = *(const float4*)&x[(size_t)(m0 + row) * IN_DIM + c4 * 4];
        const float x2a = v.x * v.x, x2b = v.y * v.y;
        const float x2c = v.z * v.z, x2d = v.w * v.w;
        uint2 s1, s2, s3;
        s1.x = pk2(v.x, v.y);         s1.y = pk2(v.z, v.w);          // x
        s2.x = pk2(x2a, x2b);         s2.y = pk2(x2c, x2d);          // x^2
        s3.x = pk2(x2a * v.x, x2b * v.y); s3.y = pk2(x2c * v.z, x2d * v.w); // x^3
        unsigned short* Ar = &A_lds[row * APAD + c4 * 4];
        *(uint2*)(Ar)       = s1;
        *(uint2*)(Ar + 128) = s2;
        *(uint2*)(Ar + 256) = s3;
    }

    __syncthreads();   // the ONLY barrier

    // ---- 12 k-steps, fully unrolled: 36 ds_read_b128 + 24 MFMA ----
    f32x4 acc0 = {0.f, 0.f, 0.f, 0.f};
    f32x4 acc1 = {0.f, 0.f, 0.f, 0.f};
    const unsigned short* Ap = &A_lds[(w * 16 + r) * APAD + q * 8];
    const unsigned short* B0 = &W_lds[r        * WPAD + q * 8];
    const unsigned short* B1 = &W_lds[(16 + r) * WPAD + q * 8];
    #pragma unroll
    for (int u = 0; u < 12; ++u) {
        const bf16x8 av = *(const bf16x8*)(Ap + u * 32);
        const bf16x8 b0 = *(const bf16x8*)(B0 + u * 32);
        const bf16x8 b1 = *(const bf16x8*)(B1 + u * 32);
        acc0 = __builtin_amdgcn_mfma_f32_16x16x32_bf16(av, b0, acc0, 0, 0, 0);
        acc1 = __builtin_amdgcn_mfma_f32_16x16x32_bf16(av, b1, acc1, 0, 0, 0);
    }

    // ---- epilogue: C/D layout col = lane&15, row = quad*4 + reg; + bias ----
    const float bb0 = bias_lds[r];
    const float bb1 = bias_lds[16 + r];
    float* obase = out + (size_t)(m0 + w * 16 + q * 4) * OUT_DIM + n0 + r;
    #pragma unroll
    for (int rr = 0; rr < 4; ++rr) {
        obase[rr * OUT_DIM]      = acc0[rr] + bb0;
        obase[rr * OUT_DIM + 16] = acc1[rr] + bb1;
    }
}

extern "C" void kernel_launch(void* const* d_in, const int* in_sizes, int n_in,
                              void* d_out, int out_size, void* d_ws, size_t ws_size,
                              hipStream_t stream) {
    const float* x     = (const float*)d_in[0];   // [8192, 128] fp32
    const float* coeff = (const float*)d_in[1];   // [16384, 4] fp32 == [128, 512]
    float* out = (float*)d_out;                   // [8192, 128] fp32

    dim3 grid(BATCH / M_BLK, OUT_DIM / N_BLK);    // 128 x 4 = 512 blocks
    kan_mfma<<<grid, 256, 0, stream>>>(x, coeff, out);
}

// Round 2
// 62.850 us; speedup vs baseline: 1.0104x; 1.0104x over previous
//
#include <hip/hip_runtime.h>

// out[b,o] = bias[o] + sum_j sum_{d=1..3} coeff[o*128+j, d] * x[b,j]^d
//   bias[o] = sum_j coeff[o*128+j, 0]   (x^0 term -> exact fp32 epilogue add)
//
// GEMM: out[M=8192, N=128] = P[M, K=384] * W[N, K=384]^T + bias
//   k = d_idx*128 + j  (d-major), d_idx=0,1,2 -> power d_idx+1
//
// R5 = R4's K=384 + fp32 bias  +  R3's staging/compute overlap:
//  - x loaded ONCE to regs (8 float4/thread, issued first vs cold HBM)
//  - plane d=1 (cheap: pk2 only) + W + bias staged -> barrier 1
//  - 8 MFMAs on plane 1 (matrix pipe) OVERLAP pow/convert/ds_write of
//    planes d=2,3 (VALU + LDS pipe) -> barrier 2 -> 16 MFMAs
//  - bias folded into W staging (coeff .x already in regs) via wave
//    shfl_xor reduce: deletes R4's 16 scalar global loads/thread
// 2 barriers. LDS 77.6 KB -> 2 blocks/CU. Grid (128,4)=512 blocks = 2/CU.

#define BATCH   8192
#define IN_DIM  128
#define OUT_DIM 128
#define KDIM    512            // raw coeff row length (floats)
#define M_BLK   64
#define N_BLK   32
#define WPAD    392            // W row stride, bf16 units (384 + 8)
#define APAD2   136            // per-plane A row stride, bf16 (128 + 8)
#define PLANE   (M_BLK * APAD2)   // 8704 shorts per d-plane

typedef __attribute__((ext_vector_type(8))) short bf16x8;
typedef __attribute__((ext_vector_type(4))) float f32x4;

__device__ inline unsigned short f2bf(float f) {
    union { float f; unsigned int u; } v; v.f = f;
    unsigned int u = v.u;
    u += 0x7FFFu + ((u >> 16) & 1u);   // round-to-nearest-even
    return (unsigned short)(u >> 16);
}

#if defined(__has_builtin)
#if __has_builtin(__builtin_amdgcn_cvt_pk_bf16_f32)
#define HAVE_HW_PKBF16 1
#endif
#endif

#ifdef HAVE_HW_PKBF16
typedef __attribute__((ext_vector_type(2))) __bf16 bf16x2_t;
__device__ inline unsigned int pk2(float a, float b) {
    bf16x2_t r = __builtin_amdgcn_cvt_pk_bf16_f32(a, b);
    union { bf16x2_t v; unsigned int u; } c; c.v = r; return c.u;
}
#else
__device__ inline unsigned int pk2(float a, float b) {
    return (unsigned int)f2bf(a) | ((unsigned int)f2bf(b) << 16);
}
#endif

__global__ __launch_bounds__(256, 2) void kan_mfma(const float* __restrict__ x,
                                                   const float* __restrict__ coeff,
                                                   float* __restrict__ out) {
    __shared__ __align__(16) unsigned short W_lds[N_BLK * WPAD];   // 25.1 KB
    __shared__ __align__(16) unsigned short A_lds[3 * PLANE];      // 52.2 KB
    __shared__ float bias_lds[N_BLK];

    const int t    = threadIdx.x;
    const int w    = t >> 6;          // wave 0..3 -> M sub-tile
    const int lane = t & 63;
    const int q    = lane >> 4;
    const int r    = lane & 15;
    const int m0   = blockIdx.x * M_BLK;
    const int n0   = blockIdx.y * N_BLK;

    // ---- issue x loads FIRST (the big cold-HBM read), 8 in flight ----
    const int arow = t >> 5;          // 0..7; 32 lanes cover one full row
    const int ac4  = t & 31;          // float4 col
    float4 xv[8];
    #pragma unroll
    for (int i = 0; i < 8; ++i)
        xv[i] = *(const float4*)&x[(size_t)(m0 + i * 8 + arow) * IN_DIM + ac4 * 4];

    // ---- W staging (once) + bias fold: 32 rows x 512 f32, coalesced ----
    {
        const int jl = lane * 2;               // even j, 0..126
        #pragma unroll
        for (int i = 0; i < 8; ++i) {
            const int wrow = i * 4 + w;
            const float* cp = &coeff[(size_t)(n0 + wrow) * KDIM + (size_t)jl * 4];
            const float4 cA = *(const float4*)cp;        // j = jl   : {c0,c1,c2,c3}
            const float4 cB = *(const float4*)(cp + 4);  // j = jl+1
            unsigned short* Wr = &W_lds[wrow * WPAD + jl];
            *(unsigned int*)(Wr)       = pk2(cA.y, cB.y);   // d=1 block
            *(unsigned int*)(Wr + 128) = pk2(cA.z, cB.z);   // d=2 block
            *(unsigned int*)(Wr + 256) = pk2(cA.w, cB.w);   // d=3 block
            // bias: c0 terms are already in regs -> wave reduce, no reload
            float b = cA.x + cB.x;
            b += __shfl_xor(b, 1);  b += __shfl_xor(b, 2);
            b += __shfl_xor(b, 4);  b += __shfl_xor(b, 8);
            b += __shfl_xor(b, 16); b += __shfl_xor(b, 32);
            if (lane == 0) bias_lds[wrow] = b;
        }
    }

    // ---- plane d=1 (cheap: pack only) ----
    #pragma unroll
    for (int i = 0; i < 8; ++i) {
        uint2 s1;
        s1.x = pk2(xv[i].x, xv[i].y);
        s1.y = pk2(xv[i].z, xv[i].w);
        *(uint2*)&A_lds[(i * 8 + arow) * APAD2 + ac4 * 4] = s1;
    }
    __syncthreads();   // barrier 1: W + plane1 + bias ready

    f32x4 acc0 = {0.f, 0.f, 0.f, 0.f};
    f32x4 acc1 = {0.f, 0.f, 0.f, 0.f};
    const unsigned short* Ap = &A_lds[(w * 16 + r) * APAD2 + q * 8];
    const unsigned short* B0 = &W_lds[r        * WPAD + q * 8];
    const unsigned short* B1 = &W_lds[(16 + r) * WPAD + q * 8];

    // ---- phase 1: 8 MFMAs on plane 1 (matrix pipe) ... ----
    #pragma unroll
    for (int u = 0; u < 4; ++u) {
        const bf16x8 av = *(const bf16x8*)(Ap + u * 32);
        const bf16x8 b0 = *(const bf16x8*)(B0 + u * 32);
        const bf16x8 b1 = *(const bf16x8*)(B1 + u * 32);
        acc0 = __builtin_amdgcn_mfma_f32_16x16x32_bf16(av, b0, acc0, 0, 0, 0);
        acc1 = __builtin_amdgcn_mfma_f32_16x16x32_bf16(av, b1, acc1, 0, 0, 0);
    }

    // ---- ... overlapped with planes d=2,3 (VALU + LDS-write pipes) ----
    #pragma unroll
    for (int i = 0; i < 8; ++i) {
        const float x2a = xv[i].x * xv[i].x, x2b = xv[i].y * xv[i].y;
        const float x2c = xv[i].z * xv[i].z, x2d = xv[i].w * xv[i].w;
        uint2 s2, s3;
        s2.x = pk2(x2a, x2b);              s2.y = pk2(x2c, x2d);
        s3.x = pk2(x2a * xv[i].x, x2b * xv[i].y);
        s3.y = pk2(x2c * xv[i].z, x2d * xv[i].w);
        unsigned short* Ar = &A_lds[(i * 8 + arow) * APAD2 + ac4 * 4];
        *(uint2*)(Ar + PLANE)     = s2;
        *(uint2*)(Ar + 2 * PLANE) = s3;
    }
    __syncthreads();   // barrier 2: planes 2,3 ready

    // ---- phase 2: 16 MFMAs on planes 2,3 ----
    #pragma unroll
    for (int u = 4; u < 12; ++u) {
        const unsigned short* Apl = Ap + (u >> 2) * PLANE + (u & 3) * 32;
        const bf16x8 av = *(const bf16x8*)(Apl);
        const bf16x8 b0 = *(const bf16x8*)(B0 + u * 32);
        const bf16x8 b1 = *(const bf16x8*)(B1 + u * 32);
        acc0 = __builtin_amdgcn_mfma_f32_16x16x32_bf16(av, b0, acc0, 0, 0, 0);
        acc1 = __builtin_amdgcn_mfma_f32_16x16x32_bf16(av, b1, acc1, 0, 0, 0);
    }

    // ---- epilogue: C/D layout col = lane&15, row = quad*4 + reg; + bias ----
    const float bb0 = bias_lds[r];
    const float bb1 = bias_lds[16 + r];
    float* obase = out + (size_t)(m0 + w * 16 + q * 4) * OUT_DIM + n0 + r;
    #pragma unroll
    for (int rr = 0; rr < 4; ++rr) {
        obase[rr * OUT_DIM]      = acc0[rr] + bb0;
        obase[rr * OUT_DIM + 16] = acc1[rr] + bb1;
    }
}

extern "C" void kernel_launch(void* const* d_in, const int* in_sizes, int n_in,
                              void* d_out, int out_size, void* d_ws, size_t ws_size,
                              hipStream_t stream) {
    const float* x     = (const float*)d_in[0];   // [8192, 128] fp32
    const float* coeff = (const float*)d_in[1];   // [16384, 4] fp32 == [128, 512]
    float* out = (float*)d_out;                   // [8192, 128] fp32

    dim3 grid(BATCH / M_BLK, OUT_DIM / N_BLK);    // 128 x 4 = 512 blocks
    kan_mfma<<<grid, 256, 0, stream>>>(x, coeff, out);
}